// Round 8
// baseline (159.442 us; speedup 1.0000x reference)
//
#include <hip/hip_runtime.h>
#include <stdint.h>

#define NH     16
#define LSEQ   2048
#define DH     64
#define HDIM   1024
#define BATCH  2

typedef __attribute__((ext_vector_type(8))) short bf16x8;
typedef __attribute__((ext_vector_type(4))) short bf16x4;
typedef __attribute__((ext_vector_type(8))) unsigned short u16x8;
typedef __attribute__((ext_vector_type(4))) float f32x4;

// fp32 -> bf16 (RNE)
static __device__ inline unsigned short f2bs(float f) {
    union { float f; uint32_t u; } v; v.f = f;
    uint32_t u = v.u;
    return (unsigned short)((u + 0x7FFFu + ((u >> 16) & 1u)) >> 16);
}
static __device__ inline float bf2f(unsigned short s) {
    return __uint_as_float(((uint32_t)s) << 16);
}

#define GLOAD_LDS(gp, lp) \
    __builtin_amdgcn_global_load_lds((const __attribute__((address_space(1))) void*)(gp), \
                                     (__attribute__((address_space(3))) void*)(lp), 16, 0, 0)

// sqrt(0.125 * log2(e)) — folded into xb so (sQ)·(sK) carries the softmax scale
#define QK_SCALE 0.42466083f

// ---------------------------------------------------------------------------
// Kernel 1: W fp32 [1024][1024] -> bf16 swizzled 128x64 tiles
//   Wbt[(nt*16 + kt)*128 + rn][chunk c at (c ^ (rn&7))], chunk = 8 shorts
// grid 512 x 256: one 16B chunk per thread.
// ---------------------------------------------------------------------------
__global__ __launch_bounds__(256) void cvt_kernel(const float* __restrict__ W,
                                                  unsigned short* __restrict__ wbt) {
    const int gid = blockIdx.x * 256 + threadIdx.x;   // 0..131071
    const int n  = gid >> 7;                          // W row
    const int kc = gid & 127;                         // 8-elem chunk in row
    const float* src = W + (size_t)n * 1024 + kc * 8;
    float4 f0 = *(const float4*)(src);
    float4 f1 = *(const float4*)(src + 4);
    u16x8 v;
    v[0]=f2bs(f0.x); v[1]=f2bs(f0.y); v[2]=f2bs(f0.z); v[3]=f2bs(f0.w);
    v[4]=f2bs(f1.x); v[5]=f2bs(f1.y); v[6]=f2bs(f1.z); v[7]=f2bs(f1.w);
    const int nt = n >> 7, rn = n & 127;
    const int kt = kc >> 3, c = kc & 7;
    *(u16x8*)(wbt + (((size_t)nt * 16 + kt) * 128 + rn) * 64 + ((c ^ (rn & 7)) * 8)) = v;
}

// ---------------------------------------------------------------------------
// Kernel 2: x fp32 [B][L][H] -> bf16 FRAGMENT-MAJOR head tiles (as round 7).
// ---------------------------------------------------------------------------
__global__ __launch_bounds__(256) void xcvt_kernel(const float* __restrict__ x,
                                                   unsigned short* __restrict__ xb,
                                                   unsigned short* __restrict__ xt) {
    const int lt = blockIdx.x, bh = blockIdx.y;
    const int b = bh >> 4, h = bh & 15;
    const int t = threadIdx.x;
    const int r = t >> 2, cp = t & 3;

    __shared__ __align__(16) unsigned short Sm[64][72];

    const float* src = x + ((size_t)(b * LSEQ + lt * 64 + r)) * HDIM + h * DH + cp * 16;
    float4 f0 = *(const float4*)(src);
    float4 f1 = *(const float4*)(src + 4);
    float4 f2 = *(const float4*)(src + 8);
    float4 f3 = *(const float4*)(src + 12);
    u16x8 lo, hi;
    lo[0]=f2bs(f0.x); lo[1]=f2bs(f0.y); lo[2]=f2bs(f0.z); lo[3]=f2bs(f0.w);
    lo[4]=f2bs(f1.x); lo[5]=f2bs(f1.y); lo[6]=f2bs(f1.z); lo[7]=f2bs(f1.w);
    hi[0]=f2bs(f2.x); hi[1]=f2bs(f2.y); hi[2]=f2bs(f2.z); hi[3]=f2bs(f2.w);
    hi[4]=f2bs(f3.x); hi[5]=f2bs(f3.y); hi[6]=f2bs(f3.z); hi[7]=f2bs(f3.w);
    u16x8 slo, shi;
    slo[0]=f2bs(f0.x*QK_SCALE); slo[1]=f2bs(f0.y*QK_SCALE); slo[2]=f2bs(f0.z*QK_SCALE); slo[3]=f2bs(f0.w*QK_SCALE);
    slo[4]=f2bs(f1.x*QK_SCALE); slo[5]=f2bs(f1.y*QK_SCALE); slo[6]=f2bs(f1.z*QK_SCALE); slo[7]=f2bs(f1.w*QK_SCALE);
    shi[0]=f2bs(f2.x*QK_SCALE); shi[1]=f2bs(f2.y*QK_SCALE); shi[2]=f2bs(f2.z*QK_SCALE); shi[3]=f2bs(f2.w*QK_SCALE);
    shi[4]=f2bs(f3.x*QK_SCALE); shi[5]=f2bs(f3.y*QK_SCALE); shi[6]=f2bs(f3.z*QK_SCALE); shi[7]=f2bs(f3.w*QK_SCALE);

    {
        unsigned short* kt = xb + ((size_t)(bh * 32 + lt)) * 4096;
        const int s  = r >> 4, la = r & 15;
        const int ks = cp >> 1, q0 = (cp & 1) * 2;
        *(u16x8*)(kt + ((s * 2 + ks) * 64 + q0 * 16 + la) * 8)       = slo;
        *(u16x8*)(kt + ((s * 2 + ks) * 64 + (q0 + 1) * 16 + la) * 8) = shi;
    }
    *(u16x8*)&Sm[r][cp * 16]     = lo;
    *(u16x8*)&Sm[r][cp * 16 + 8] = hi;
    __syncthreads();

    {
        const int dt = t >> 6, lane = t & 63;
        const int la = lane & 15, quad = lane >> 4;
        u16x8 g0, g1;
        #pragma unroll
        for (int kvt = 0; kvt < 2; ++kvt)
            #pragma unroll
            for (int j = 0; j < 4; ++j)
                g0[kvt * 4 + j] = Sm[kvt * 16 + quad * 4 + j][dt * 16 + la];
        #pragma unroll
        for (int kvt = 0; kvt < 2; ++kvt)
            #pragma unroll
            for (int j = 0; j < 4; ++j)
                g1[kvt * 4 + j] = Sm[(kvt + 2) * 16 + quad * 4 + j][dt * 16 + la];
        unsigned short* vt = xt + ((size_t)(bh * 32 + lt)) * 4096;
        *(u16x8*)(vt + (dt * 64 + lane) * 16)     = g0;
        *(u16x8*)(vt + (dt * 64 + lane) * 16 + 8) = g1;
    }
}

// ---------------------------------------------------------------------------
// Kernel 3: flash attention, transpose-free (round-7 structure), KV-split KS.
// grid (32 bh, 16 qt, KS); each block does nt_tiles = 32/KS KV tiles.
// ---------------------------------------------------------------------------
__global__ __launch_bounds__(256) void attn_kernel(const unsigned short* __restrict__ xb,
                                                   const unsigned short* __restrict__ xt,
                                                   unsigned short* __restrict__ po,
                                                   float* __restrict__ pl,
                                                   int nt_tiles) {
    const int bh = blockIdx.x;
    const int qt = blockIdx.y;
    const int ksb = blockIdx.z;
    const int tid = threadIdx.x;
    const int w = tid >> 6, lane = tid & 63;
    const int la = lane & 15, quad = lane >> 4;

    __shared__ __align__(16) unsigned short KL[2][4096];
    __shared__ __align__(16) unsigned short VL[2][4096];

    const unsigned short* xbh = xb + (size_t)bh * 32 * 4096;
    const unsigned short* xth = xt + (size_t)bh * 32 * 4096;
    const int qbase = qt * 128 + w * 32;
    const int t0 = ksb * nt_tiles;

    bf16x8 qf[2][2];
    #pragma unroll
    for (int qnt = 0; qnt < 2; ++qnt) {
        const int q0 = qbase + qnt * 16;
        const unsigned short* qs = xbh + (q0 >> 6) * 4096 + (((q0 >> 4) & 3) * 2) * 512;
        qf[qnt][0] = *(const bf16x8*)(qs + lane * 8);
        qf[qnt][1] = *(const bf16x8*)(qs + 512 + lane * 8);
    }

    const f32x4 fzero = {0.f, 0.f, 0.f, 0.f};
    f32x4 acc[2][4];
    #pragma unroll
    for (int i = 0; i < 2; ++i)
        #pragma unroll
        for (int j = 0; j < 4; ++j) acc[i][j] = fzero;
    float lp[2] = {0.f, 0.f};

    #pragma unroll
    for (int j = 0; j < 2; ++j) {
        const int off = (j * 256 + tid) * 16;
        GLOAD_LDS((const char*)(xbh + t0 * 4096) + off, (char*)KL[0] + off);
        GLOAD_LDS((const char*)(xth + t0 * 4096) + off, (char*)VL[0] + off);
    }
    __syncthreads();

    for (int tt = 0; tt < nt_tiles; ++tt) {
        if (tt < nt_tiles - 1) {
            const char* ksrc = (const char*)(xbh + (t0 + tt + 1) * 4096);
            char* kdst = (char*)KL[(tt + 1) & 1];
            #pragma unroll
            for (int j = 0; j < 2; ++j) {
                const int off = (j * 256 + tid) * 16;
                GLOAD_LDS(ksrc + off, kdst + off);
            }
        }

        const unsigned short* kb = KL[tt & 1];
        f32x4 st[4][2];
        #pragma unroll
        for (int kvt = 0; kvt < 4; ++kvt) {
            bf16x8 kf0 = *(const bf16x8*)(kb + (kvt * 2 + 0) * 512 + lane * 8);
            bf16x8 kf1 = *(const bf16x8*)(kb + (kvt * 2 + 1) * 512 + lane * 8);
            #pragma unroll
            for (int qnt = 0; qnt < 2; ++qnt) {
                f32x4 s = fzero;
                s = __builtin_amdgcn_mfma_f32_16x16x32_bf16(kf0, qf[qnt][0], s, 0, 0, 0);
                s = __builtin_amdgcn_mfma_f32_16x16x32_bf16(kf1, qf[qnt][1], s, 0, 0, 0);
                st[kvt][qnt] = s;
            }
        }

        bf16x4 pf[2][4];
        #pragma unroll
        for (int qnt = 0; qnt < 2; ++qnt) {
            float ls = 0.f;
            #pragma unroll
            for (int kvt = 0; kvt < 4; ++kvt) {
                float p0 = __builtin_amdgcn_exp2f(st[kvt][qnt][0]);
                float p1 = __builtin_amdgcn_exp2f(st[kvt][qnt][1]);
                float p2 = __builtin_amdgcn_exp2f(st[kvt][qnt][2]);
                float p3 = __builtin_amdgcn_exp2f(st[kvt][qnt][3]);
                ls += (p0 + p1) + (p2 + p3);
                uint32_t u0 = __float_as_uint(p0) + 0x8000u;
                uint32_t u1 = __float_as_uint(p1) + 0x8000u;
                uint32_t u2 = __float_as_uint(p2) + 0x8000u;
                uint32_t u3 = __float_as_uint(p3) + 0x8000u;
                union { uint2 u; bf16x4 v; } cv;
                cv.u = make_uint2(__builtin_amdgcn_perm(u1, u0, 0x07060302),
                                  __builtin_amdgcn_perm(u3, u2, 0x07060302));
                pf[qnt][kvt] = cv.v;
            }
            lp[qnt] += ls;
        }

        __syncthreads();

        if (tt < nt_tiles - 1) {
            const char* vsrc = (const char*)(xth + (t0 + tt + 1) * 4096);
            char* vdst = (char*)VL[(tt + 1) & 1];
            #pragma unroll
            for (int j = 0; j < 2; ++j) {
                const int off = (j * 256 + tid) * 16;
                GLOAD_LDS(vsrc + off, vdst + off);
            }
        }

        const unsigned short* vb = VL[tt & 1];
        #pragma unroll
        for (int dt = 0; dt < 4; ++dt) {
            const unsigned short* vrow = vb + (dt * 64 + lane) * 16;
            #pragma unroll
            for (int kvt = 0; kvt < 4; ++kvt) {
                bf16x4 vf = *(const bf16x4*)(vrow + kvt * 4);
                #pragma unroll
                for (int qnt = 0; qnt < 2; ++qnt)
                    acc[qnt][dt] = __builtin_amdgcn_mfma_f32_16x16x16bf16_1k(
                        vf, pf[qnt][kvt], acc[qnt][dt], 0, 0, 0);
            }
        }
    }

    const size_t prow = (size_t)(ksb * 32 + bh) * 2048 + qbase;
    unsigned short* pob = po + prow * 64;
    #pragma unroll
    for (int qnt = 0; qnt < 2; ++qnt) {
        unsigned short* orow = pob + (size_t)(qnt * 16 + la) * 64 + quad * 4;
        #pragma unroll
        for (int dt = 0; dt < 4; ++dt) {
            f32x4 a = acc[qnt][dt];
            *(ushort4*)(orow + dt * 16) =
                make_ushort4(f2bs(a[0]), f2bs(a[1]), f2bs(a[2]), f2bs(a[3]));
        }
    }
    #pragma unroll
    for (int qnt = 0; qnt < 2; ++qnt) {
        float l = lp[qnt];
        l += __shfl_xor(l, 16);
        l += __shfl_xor(l, 32);
        if (quad == 0) pl[prow + qnt * 16 + la] = l;
    }
}

// ---------------------------------------------------------------------------
// Kernel 4: combine KS KV-splits -> ctx in swizzled 128x64 proj tiles.
//   ctxt[(mt*16 + h)*128 + r][chunk c at (c ^ (r&7))], m = b*2048+q
// ---------------------------------------------------------------------------
__global__ __launch_bounds__(256) void reduce_kernel(const unsigned short* __restrict__ po,
                                                     const float* __restrict__ pl,
                                                     unsigned short* __restrict__ ctxt,
                                                     int KS) {
    const int gid = blockIdx.x * 256 + threadIdx.x;
    const int rid = gid >> 4;                       // bh*2048 + q
    const int d0  = (gid & 15) * 4;
    float l = 0.f;
    for (int s = 0; s < KS; ++s) l += pl[(size_t)s * 65536 + rid];
    const float invl = 1.0f / l;
    float o0 = 0.f, o1 = 0.f, o2 = 0.f, o3 = 0.f;
    for (int s = 0; s < KS; ++s) {
        ushort4 a = *(const ushort4*)(po + ((size_t)s * 65536 + rid) * 64 + d0);
        o0 += bf2f(a.x); o1 += bf2f(a.y); o2 += bf2f(a.z); o3 += bf2f(a.w);
    }
    const int bh = rid >> 11, q = rid & 2047;
    const int b = bh >> 4, h = bh & 15;
    const int m = b * 2048 + q;
    const int mt = m >> 7, r = m & 127;
    const int c = d0 >> 3, off = d0 & 7;
    unsigned short* dst = ctxt + (((size_t)mt * 16 + h) * 128 + r) * 64 + ((c ^ (r & 7)) * 8) + off;
    *(ushort4*)dst = make_ushort4(f2bs(o0 * invl), f2bs(o1 * invl),
                                  f2bs(o2 * invl), f2bs(o3 * invl));
}

// ---------------------------------------------------------------------------
// Kernel 5: out = ctx @ W^T + b. m97 structure: 128x128 tile, BK=64,
// double-buffered LDS (64 KB), one barrier/iter, 32 MFMA/iter, flat
// global_load_lds staging of pre-swizzled tiles, conflict-free b128 frags.
// grid (8 n, 32 m), block 256 = 4 waves (2x2 64x64 quadrants).
// ---------------------------------------------------------------------------
__global__ __launch_bounds__(256) void proj_kernel(const unsigned short* __restrict__ ctxt,
                                                   const unsigned short* __restrict__ wbt,
                                                   const float* __restrict__ bias,
                                                   float* __restrict__ out) {
    const int ntb = blockIdx.x;         // 0..7
    const int mtb = blockIdx.y;         // 0..31
    const int tid = threadIdx.x;
    const int w = tid >> 6, lane = tid & 63;
    const int la = lane & 15, quad = lane >> 4;
    const int wm = (w >> 1) * 64, wn = (w & 1) * 64;

    __shared__ __align__(16) unsigned short As[2][8192];
    __shared__ __align__(16) unsigned short Bs[2][8192];

    const unsigned short* abase = ctxt + (size_t)mtb * 16 * 8192;
    const unsigned short* bbase = wbt  + (size_t)ntb * 16 * 8192;

    const int sw0 = ((quad)     ^ (la & 7)) * 8;   // chunk ks2=0
    const int sw1 = ((quad + 4) ^ (la & 7)) * 8;   // chunk ks2=1

    const f32x4 fzero = {0.f, 0.f, 0.f, 0.f};
    f32x4 acc[4][4];
    #pragma unroll
    for (int i = 0; i < 4; ++i)
        #pragma unroll
        for (int j = 0; j < 4; ++j) acc[i][j] = fzero;

    // prologue: stage kt=0 into buffer 0
    #pragma unroll
    for (int j = 0; j < 4; ++j) {
        const int fc = j * 256 + tid;              // 16B chunk 0..1023
        GLOAD_LDS((const char*)abase + fc * 16, (char*)As[0] + fc * 16);
        GLOAD_LDS((const char*)bbase + fc * 16, (char*)Bs[0] + fc * 16);
    }
    __syncthreads();

    for (int kt = 0; kt < 16; ++kt) {
        // stage kt+1 into the other buffer (drained by this iter's end barrier)
        if (kt < 15) {
            const char* asrc = (const char*)(abase + (kt + 1) * 8192);
            const char* bsrc = (const char*)(bbase + (kt + 1) * 8192);
            char* adst = (char*)As[(kt + 1) & 1];
            char* bdst = (char*)Bs[(kt + 1) & 1];
            #pragma unroll
            for (int j = 0; j < 4; ++j) {
                const int fc = j * 256 + tid;
                GLOAD_LDS(asrc + fc * 16, adst + fc * 16);
                GLOAD_LDS(bsrc + fc * 16, bdst + fc * 16);
            }
        }

        const unsigned short* Ab = As[kt & 1];
        const unsigned short* Bb = Bs[kt & 1];
        #pragma unroll
        for (int ks2 = 0; ks2 < 2; ++ks2) {
            const int sw = ks2 ? sw1 : sw0;
            bf16x8 af[4], bfr[4];
            #pragma unroll
            for (int mt = 0; mt < 4; ++mt) af[mt]  = *(const bf16x8*)&Ab[(wm + mt * 16 + la) * 64 + sw];
            #pragma unroll
            for (int nt = 0; nt < 4; ++nt) bfr[nt] = *(const bf16x8*)&Bb[(wn + nt * 16 + la) * 64 + sw];
            #pragma unroll
            for (int mt = 0; mt < 4; ++mt)
                #pragma unroll
                for (int nt = 0; nt < 4; ++nt)
                    acc[mt][nt] = __builtin_amdgcn_mfma_f32_16x16x32_bf16(af[mt], bfr[nt], acc[mt][nt], 0, 0, 0);
        }
        __syncthreads();
    }

    const int m0 = mtb * 128, n0 = ntb * 128;
    #pragma unroll
    for (int nt = 0; nt < 4; ++nt) {
        const int n = n0 + wn + nt * 16 + la;
        const float bv = bias[n];
        #pragma unroll
        for (int mt = 0; mt < 4; ++mt)
            #pragma unroll
            for (int r = 0; r < 4; ++r) {
                const int m = m0 + wm + mt * 16 + quad * 4 + r;
                out[(size_t)m * HDIM + n] = acc[mt][nt][r] + bv;
            }
    }
}

// ---------------------------------------------------------------------------
extern "C" void kernel_launch(void* const* d_in, const int* in_sizes, int n_in,
                              void* d_out, int out_size, void* d_ws, size_t ws_size,
                              hipStream_t stream) {
    const float* x    = (const float*)d_in[0];
    const float* W    = (const float*)d_in[1];
    const float* bias = (const float*)d_in[2];
    float* out = (float*)d_out;

    // KV-split factor chosen by workspace capacity (constant across calls)
    const int KS = (ws_size >= (60u << 20)) ? 4 : 2;

    // ws layout (bytes): ctxt 8M | xb 8M | xt 8M | Wbt 2M | pl 1M | po KS*8M
    unsigned short* ctxt = (unsigned short*)d_ws;
    unsigned short* xbp  = (unsigned short*)((char*)d_ws + ( 8u << 20));
    unsigned short* xtp  = (unsigned short*)((char*)d_ws + (16u << 20));
    unsigned short* wbt  = (unsigned short*)((char*)d_ws + (24u << 20));
    float*          pl   = (float*)         ((char*)d_ws + (26u << 20));
    unsigned short* po   = (unsigned short*)((char*)d_ws + (27u << 20));

    cvt_kernel<<<dim3(512), 256, 0, stream>>>(W, wbt);
    xcvt_kernel<<<dim3(32, 32), 256, 0, stream>>>(x, xbp, xtp);
    attn_kernel<<<dim3(32, 16, KS), 256, 0, stream>>>(xbp, xtp, po, pl, 32 / KS);
    reduce_kernel<<<dim3(4096), 256, 0, stream>>>(po, pl, ctxt, KS);
    proj_kernel<<<dim3(8, 32), 256, 0, stream>>>(ctxt, wbt, bias, out);
}

// Round 10
// 153.606 us; speedup vs baseline: 1.0380x; 1.0380x over previous
//
#include <hip/hip_runtime.h>
#include <stdint.h>

#define NH     16
#define LSEQ   2048
#define DH     64
#define HDIM   1024
#define BATCH  2

typedef __attribute__((ext_vector_type(8))) short bf16x8;
typedef __attribute__((ext_vector_type(4))) short bf16x4;
typedef __attribute__((ext_vector_type(8))) unsigned short u16x8;
typedef __attribute__((ext_vector_type(4))) float f32x4;

// fp32 -> bf16 (RNE)
static __device__ inline unsigned short f2bs(float f) {
    union { float f; uint32_t u; } v; v.f = f;
    uint32_t u = v.u;
    return (unsigned short)((u + 0x7FFFu + ((u >> 16) & 1u)) >> 16);
}

#define GLOAD_LDS(gp, lp) \
    __builtin_amdgcn_global_load_lds((const __attribute__((address_space(1))) void*)(gp), \
                                     (__attribute__((address_space(3))) void*)(lp), 16, 0, 0)

// sqrt(0.125 * log2(e)) — folded into xb so (sQ)·(sK) carries the softmax scale
#define QK_SCALE 0.42466083f

// ---------------------------------------------------------------------------
// Kernel 1: prep. grid (32 lt, 32 bh) = 1024 blocks, 256 thr.
//  a) threads 0..127: W fp32 -> bf16 swizzled 128x64 tiles (128 chunks/block)
//  b) all threads: x -> xb (frag-major Q/K, scaled) and xt (frag-major V^T)
// ---------------------------------------------------------------------------
__global__ __launch_bounds__(256) void prep_kernel(const float* __restrict__ x,
                                                   const float* __restrict__ W,
                                                   unsigned short* __restrict__ xb,
                                                   unsigned short* __restrict__ xt,
                                                   unsigned short* __restrict__ wbt) {
    const int lt = blockIdx.x, bh = blockIdx.y;
    const int bid = bh * 32 + lt;
    const int t = threadIdx.x;

    // --- W conversion: 128 chunks per block on threads 0..127 ---
    if (t < 128) {
        const int gid = bid * 128 + t;            // 0..131071
        const int n  = gid >> 7;                  // W row
        const int kc = gid & 127;                 // 8-elem chunk
        const float* src = W + (size_t)n * 1024 + kc * 8;
        float4 f0 = *(const float4*)(src);
        float4 f1 = *(const float4*)(src + 4);
        u16x8 v;
        v[0]=f2bs(f0.x); v[1]=f2bs(f0.y); v[2]=f2bs(f0.z); v[3]=f2bs(f0.w);
        v[4]=f2bs(f1.x); v[5]=f2bs(f1.y); v[6]=f2bs(f1.z); v[7]=f2bs(f1.w);
        const int nt = n >> 7, rn = n & 127;
        const int kt = kc >> 3, c = kc & 7;
        *(u16x8*)(wbt + (((size_t)nt * 16 + kt) * 128 + rn) * 64 + ((c ^ (rn & 7)) * 8)) = v;
    }

    // --- x conversion (round-8 xcvt body) ---
    const int b = bh >> 4, h = bh & 15;
    const int r = t >> 2, cp = t & 3;

    __shared__ __align__(16) unsigned short Sm[64][72];

    const float* src = x + ((size_t)(b * LSEQ + lt * 64 + r)) * HDIM + h * DH + cp * 16;
    float4 f0 = *(const float4*)(src);
    float4 f1 = *(const float4*)(src + 4);
    float4 f2 = *(const float4*)(src + 8);
    float4 f3 = *(const float4*)(src + 12);
    u16x8 lo, hi;
    lo[0]=f2bs(f0.x); lo[1]=f2bs(f0.y); lo[2]=f2bs(f0.z); lo[3]=f2bs(f0.w);
    lo[4]=f2bs(f1.x); lo[5]=f2bs(f1.y); lo[6]=f2bs(f1.z); lo[7]=f2bs(f1.w);
    hi[0]=f2bs(f2.x); hi[1]=f2bs(f2.y); hi[2]=f2bs(f2.z); hi[3]=f2bs(f2.w);
    hi[4]=f2bs(f3.x); hi[5]=f2bs(f3.y); hi[6]=f2bs(f3.z); hi[7]=f2bs(f3.w);
    u16x8 slo, shi;
    slo[0]=f2bs(f0.x*QK_SCALE); slo[1]=f2bs(f0.y*QK_SCALE); slo[2]=f2bs(f0.z*QK_SCALE); slo[3]=f2bs(f0.w*QK_SCALE);
    slo[4]=f2bs(f1.x*QK_SCALE); slo[5]=f2bs(f1.y*QK_SCALE); slo[6]=f2bs(f1.z*QK_SCALE); slo[7]=f2bs(f1.w*QK_SCALE);
    shi[0]=f2bs(f2.x*QK_SCALE); shi[1]=f2bs(f2.y*QK_SCALE); shi[2]=f2bs(f2.z*QK_SCALE); shi[3]=f2bs(f2.w*QK_SCALE);
    shi[4]=f2bs(f3.x*QK_SCALE); shi[5]=f2bs(f3.y*QK_SCALE); shi[6]=f2bs(f3.z*QK_SCALE); shi[7]=f2bs(f3.w*QK_SCALE);

    {
        unsigned short* kt = xb + ((size_t)bid) * 4096;
        const int s  = r >> 4, rla = r & 15;
        const int ks = cp >> 1, q0 = (cp & 1) * 2;
        *(u16x8*)(kt + ((s * 2 + ks) * 64 + q0 * 16 + rla) * 8)       = slo;
        *(u16x8*)(kt + ((s * 2 + ks) * 64 + (q0 + 1) * 16 + rla) * 8) = shi;
    }
    *(u16x8*)&Sm[r][cp * 16]     = lo;
    *(u16x8*)&Sm[r][cp * 16 + 8] = hi;
    __syncthreads();

    {
        const int dt = t >> 6, lane = t & 63;
        const int la = lane & 15, quad = lane >> 4;
        u16x8 g0, g1;
        #pragma unroll
        for (int kvt = 0; kvt < 2; ++kvt)
            #pragma unroll
            for (int j = 0; j < 4; ++j)
                g0[kvt * 4 + j] = Sm[kvt * 16 + quad * 4 + j][dt * 16 + la];
        #pragma unroll
        for (int kvt = 0; kvt < 2; ++kvt)
            #pragma unroll
            for (int j = 0; j < 4; ++j)
                g1[kvt * 4 + j] = Sm[(kvt + 2) * 16 + quad * 4 + j][dt * 16 + la];
        unsigned short* vt = xt + ((size_t)bid) * 4096;
        *(u16x8*)(vt + (dt * 64 + lane) * 16)     = g0;
        *(u16x8*)(vt + (dt * 64 + lane) * 16 + 8) = g1;
    }
}

// ---------------------------------------------------------------------------
// Kernel 2: flash attention, transpose-free, KS=1 (full KV per block).
// grid (32 bh, 16 qt) = 512 blocks. Epilogue normalizes in-register and
// writes ctx DIRECTLY in swizzled proj-A tile layout (no reduce pass):
//   ctxt[(mt*16 + h)*128 + rr][chunk c at (c ^ (rr&7))], mt = b*16+qt,
//   rr = w*32 + qnt*16 + la, c = dt*2 + (quad>>1), in-chunk off (quad&1)*4.
// ---------------------------------------------------------------------------
__global__ __launch_bounds__(256) void attn_kernel(const unsigned short* __restrict__ xb,
                                                   const unsigned short* __restrict__ xt,
                                                   unsigned short* __restrict__ ctxt) {
    const int bh = blockIdx.x;
    const int qt = blockIdx.y;
    const int tid = threadIdx.x;
    const int w = tid >> 6, lane = tid & 63;
    const int la = lane & 15, quad = lane >> 4;

    __shared__ __align__(16) unsigned short KL[2][4096];
    __shared__ __align__(16) unsigned short VL[2][4096];

    const unsigned short* xbh = xb + (size_t)bh * 32 * 4096;
    const unsigned short* xth = xt + (size_t)bh * 32 * 4096;
    const int qbase = qt * 128 + w * 32;

    bf16x8 qf[2][2];
    #pragma unroll
    for (int qnt = 0; qnt < 2; ++qnt) {
        const int q0 = qbase + qnt * 16;
        const unsigned short* qs = xbh + (q0 >> 6) * 4096 + (((q0 >> 4) & 3) * 2) * 512;
        qf[qnt][0] = *(const bf16x8*)(qs + lane * 8);
        qf[qnt][1] = *(const bf16x8*)(qs + 512 + lane * 8);
    }

    const f32x4 fzero = {0.f, 0.f, 0.f, 0.f};
    f32x4 acc[2][4];
    #pragma unroll
    for (int i = 0; i < 2; ++i)
        #pragma unroll
        for (int j = 0; j < 4; ++j) acc[i][j] = fzero;
    float lp[2] = {0.f, 0.f};

    #pragma unroll
    for (int j = 0; j < 2; ++j) {
        const int off = (j * 256 + tid) * 16;
        GLOAD_LDS((const char*)xbh + off, (char*)KL[0] + off);
        GLOAD_LDS((const char*)xth + off, (char*)VL[0] + off);
    }
    __syncthreads();

    for (int tt = 0; tt < 32; ++tt) {
        if (tt < 31) {
            const char* ksrc = (const char*)(xbh + (tt + 1) * 4096);
            char* kdst = (char*)KL[(tt + 1) & 1];
            #pragma unroll
            for (int j = 0; j < 2; ++j) {
                const int off = (j * 256 + tid) * 16;
                GLOAD_LDS(ksrc + off, kdst + off);
            }
        }

        const unsigned short* kb = KL[tt & 1];
        f32x4 st[4][2];
        #pragma unroll
        for (int kvt = 0; kvt < 4; ++kvt) {
            bf16x8 kf0 = *(const bf16x8*)(kb + (kvt * 2 + 0) * 512 + lane * 8);
            bf16x8 kf1 = *(const bf16x8*)(kb + (kvt * 2 + 1) * 512 + lane * 8);
            #pragma unroll
            for (int qnt = 0; qnt < 2; ++qnt) {
                f32x4 s = fzero;
                s = __builtin_amdgcn_mfma_f32_16x16x32_bf16(kf0, qf[qnt][0], s, 0, 0, 0);
                s = __builtin_amdgcn_mfma_f32_16x16x32_bf16(kf1, qf[qnt][1], s, 0, 0, 0);
                st[kvt][qnt] = s;
            }
        }

        bf16x4 pf[2][4];
        #pragma unroll
        for (int qnt = 0; qnt < 2; ++qnt) {
            float ls = 0.f;
            #pragma unroll
            for (int kvt = 0; kvt < 4; ++kvt) {
                float p0 = __builtin_amdgcn_exp2f(st[kvt][qnt][0]);
                float p1 = __builtin_amdgcn_exp2f(st[kvt][qnt][1]);
                float p2 = __builtin_amdgcn_exp2f(st[kvt][qnt][2]);
                float p3 = __builtin_amdgcn_exp2f(st[kvt][qnt][3]);
                ls += (p0 + p1) + (p2 + p3);
                uint32_t u0 = __float_as_uint(p0) + 0x8000u;
                uint32_t u1 = __float_as_uint(p1) + 0x8000u;
                uint32_t u2 = __float_as_uint(p2) + 0x8000u;
                uint32_t u3 = __float_as_uint(p3) + 0x8000u;
                union { uint2 u; bf16x4 v; } cv;
                cv.u = make_uint2(__builtin_amdgcn_perm(u1, u0, 0x07060302),
                                  __builtin_amdgcn_perm(u3, u2, 0x07060302));
                pf[qnt][kvt] = cv.v;
            }
            lp[qnt] += ls;
        }

        __syncthreads();

        if (tt < 31) {
            const char* vsrc = (const char*)(xth + (tt + 1) * 4096);
            char* vdst = (char*)VL[(tt + 1) & 1];
            #pragma unroll
            for (int j = 0; j < 2; ++j) {
                const int off = (j * 256 + tid) * 16;
                GLOAD_LDS(vsrc + off, vdst + off);
            }
        }

        const unsigned short* vb = VL[tt & 1];
        #pragma unroll
        for (int dt = 0; dt < 4; ++dt) {
            const unsigned short* vrow = vb + (dt * 64 + lane) * 16;
            #pragma unroll
            for (int kvt = 0; kvt < 4; ++kvt) {
                bf16x4 vf = *(const bf16x4*)(vrow + kvt * 4);
                #pragma unroll
                for (int qnt = 0; qnt < 2; ++qnt)
                    acc[qnt][dt] = __builtin_amdgcn_mfma_f32_16x16x16bf16_1k(
                        vf, pf[qnt][kvt], acc[qnt][dt], 0, 0, 0);
            }
        }
    }

    // --- epilogue: normalize in-register, write swizzled proj-A ctx tiles ---
    const int b = bh >> 4, h = bh & 15;
    const int mt = b * 16 + qt;
    unsigned short* tbase = ctxt + ((size_t)mt * 16 + h) * 128 * 64;
    #pragma unroll
    for (int qnt = 0; qnt < 2; ++qnt) {
        float l = lp[qnt];
        l += __shfl_xor(l, 16);
        l += __shfl_xor(l, 32);
        const float inv = 1.0f / l;          // l for q = qnt*16+la (uniform over quads)
        const int rr = w * 32 + qnt * 16 + la;
        unsigned short* rowp = tbase + rr * 64 + (quad & 1) * 4;
        #pragma unroll
        for (int dt = 0; dt < 4; ++dt) {
            f32x4 a = acc[qnt][dt];
            const int c = dt * 2 + (quad >> 1);
            *(ushort4*)(rowp + ((c ^ (rr & 7)) * 8)) =
                make_ushort4(f2bs(a[0] * inv), f2bs(a[1] * inv),
                             f2bs(a[2] * inv), f2bs(a[3] * inv));
        }
    }
}

// ---------------------------------------------------------------------------
// Kernel 3: out = ctx @ W^T + b. 128x128 tile, BK=64, double-buffered LDS,
// one barrier/iter, flat global_load_lds of pre-swizzled tiles (round-8).
// grid (8 n, 32 m), block 256 = 4 waves (2x2 64x64 quadrants).
// ---------------------------------------------------------------------------
__global__ __launch_bounds__(256) void proj_kernel(const unsigned short* __restrict__ ctxt,
                                                   const unsigned short* __restrict__ wbt,
                                                   const float* __restrict__ bias,
                                                   float* __restrict__ out) {
    const int ntb = blockIdx.x;
    const int mtb = blockIdx.y;
    const int tid = threadIdx.x;
    const int w = tid >> 6, lane = tid & 63;
    const int la = lane & 15, quad = lane >> 4;
    const int wm = (w >> 1) * 64, wn = (w & 1) * 64;

    __shared__ __align__(16) unsigned short As[2][8192];
    __shared__ __align__(16) unsigned short Bs[2][8192];

    const unsigned short* abase = ctxt + (size_t)mtb * 16 * 8192;
    const unsigned short* bbase = wbt  + (size_t)ntb * 16 * 8192;

    const int sw0 = ((quad)     ^ (la & 7)) * 8;
    const int sw1 = ((quad + 4) ^ (la & 7)) * 8;

    const f32x4 fzero = {0.f, 0.f, 0.f, 0.f};
    f32x4 acc[4][4];
    #pragma unroll
    for (int i = 0; i < 4; ++i)
        #pragma unroll
        for (int j = 0; j < 4; ++j) acc[i][j] = fzero;

    #pragma unroll
    for (int j = 0; j < 4; ++j) {
        const int fc = j * 256 + tid;
        GLOAD_LDS((const char*)abase + fc * 16, (char*)As[0] + fc * 16);
        GLOAD_LDS((const char*)bbase + fc * 16, (char*)Bs[0] + fc * 16);
    }
    __syncthreads();

    for (int kt = 0; kt < 16; ++kt) {
        if (kt < 15) {
            const char* asrc = (const char*)(abase + (kt + 1) * 8192);
            const char* bsrc = (const char*)(bbase + (kt + 1) * 8192);
            char* adst = (char*)As[(kt + 1) & 1];
            char* bdst = (char*)Bs[(kt + 1) & 1];
            #pragma unroll
            for (int j = 0; j < 4; ++j) {
                const int fc = j * 256 + tid;
                GLOAD_LDS(asrc + fc * 16, adst + fc * 16);
                GLOAD_LDS(bsrc + fc * 16, bdst + fc * 16);
            }
        }

        const unsigned short* Ab = As[kt & 1];
        const unsigned short* Bb = Bs[kt & 1];
        #pragma unroll
        for (int ks2 = 0; ks2 < 2; ++ks2) {
            const int sw = ks2 ? sw1 : sw0;
            bf16x8 af[4], bfr[4];
            #pragma unroll
            for (int mt = 0; mt < 4; ++mt) af[mt]  = *(const bf16x8*)&Ab[(wm + mt * 16 + la) * 64 + sw];
            #pragma unroll
            for (int nt = 0; nt < 4; ++nt) bfr[nt] = *(const bf16x8*)&Bb[(wn + nt * 16 + la) * 64 + sw];
            #pragma unroll
            for (int mt = 0; mt < 4; ++mt)
                #pragma unroll
                for (int nt = 0; nt < 4; ++nt)
                    acc[mt][nt] = __builtin_amdgcn_mfma_f32_16x16x32_bf16(af[mt], bfr[nt], acc[mt][nt], 0, 0, 0);
        }
        __syncthreads();
    }

    const int m0 = mtb * 128, n0 = ntb * 128;
    #pragma unroll
    for (int nt = 0; nt < 4; ++nt) {
        const int n = n0 + wn + nt * 16 + la;
        const float bv = bias[n];
        #pragma unroll
        for (int mt = 0; mt < 4; ++mt)
            #pragma unroll
            for (int r = 0; r < 4; ++r) {
                const int m = m0 + wm + mt * 16 + quad * 4 + r;
                out[(size_t)m * HDIM + n] = acc[mt][nt][r] + bv;
            }
    }
}

// ---------------------------------------------------------------------------
extern "C" void kernel_launch(void* const* d_in, const int* in_sizes, int n_in,
                              void* d_out, int out_size, void* d_ws, size_t ws_size,
                              hipStream_t stream) {
    const float* x    = (const float*)d_in[0];
    const float* W    = (const float*)d_in[1];
    const float* bias = (const float*)d_in[2];
    float* out = (float*)d_out;

    // ws layout (bytes): ctxt 8M | xb 8M | xt 8M | wbt 2M
    unsigned short* ctxt = (unsigned short*)d_ws;
    unsigned short* xbp  = (unsigned short*)((char*)d_ws + ( 8u << 20));
    unsigned short* xtp  = (unsigned short*)((char*)d_ws + (16u << 20));
    unsigned short* wbt  = (unsigned short*)((char*)d_ws + (24u << 20));

    prep_kernel<<<dim3(32, 32), 256, 0, stream>>>(x, W, xbp, xtp, wbt);
    attn_kernel<<<dim3(32, 16), 256, 0, stream>>>(xbp, xtp, ctxt);
    proj_kernel<<<dim3(8, 32), 256, 0, stream>>>(ctxt, wbt, bias, out);
}

// Round 11
// 149.101 us; speedup vs baseline: 1.0694x; 1.0302x over previous
//
#include <hip/hip_runtime.h>
#include <stdint.h>

#define NH     16
#define LSEQ   2048
#define DH     64
#define HDIM   1024
#define BATCH  2

typedef __attribute__((ext_vector_type(8))) short bf16x8;
typedef __attribute__((ext_vector_type(4))) short bf16x4;
typedef __attribute__((ext_vector_type(8))) unsigned short u16x8;
typedef __attribute__((ext_vector_type(4))) float f32x4;

// fp32 -> bf16 (RNE)
static __device__ inline unsigned short f2bs(float f) {
    union { float f; uint32_t u; } v; v.f = f;
    uint32_t u = v.u;
    return (unsigned short)((u + 0x7FFFu + ((u >> 16) & 1u)) >> 16);
}

#define GLOAD_LDS(gp, lp) \
    __builtin_amdgcn_global_load_lds((const __attribute__((address_space(1))) void*)(gp), \
                                     (__attribute__((address_space(3))) void*)(lp), 16, 0, 0)

// sqrt(0.125 * log2(e)) — folded into xb so (sQ)·(sK) carries the softmax scale
#define QK_SCALE 0.42466083f

// ---------------------------------------------------------------------------
// Kernel 1: prep. grid (32 lt, 32 bh) = 1024 blocks, 256 thr.
//  a) threads 0..127: W fp32 -> bf16 swizzled 128x64 tiles (128 chunks/block)
//  b) all threads: x -> xb (frag-major Q/K, scaled) and xt (frag-major V^T)
// ---------------------------------------------------------------------------
__global__ __launch_bounds__(256) void prep_kernel(const float* __restrict__ x,
                                                   const float* __restrict__ W,
                                                   unsigned short* __restrict__ xb,
                                                   unsigned short* __restrict__ xt,
                                                   unsigned short* __restrict__ wbt) {
    const int lt = blockIdx.x, bh = blockIdx.y;
    const int bid = bh * 32 + lt;
    const int t = threadIdx.x;

    if (t < 128) {
        const int gid = bid * 128 + t;
        const int n  = gid >> 7;
        const int kc = gid & 127;
        const float* src = W + (size_t)n * 1024 + kc * 8;
        float4 f0 = *(const float4*)(src);
        float4 f1 = *(const float4*)(src + 4);
        u16x8 v;
        v[0]=f2bs(f0.x); v[1]=f2bs(f0.y); v[2]=f2bs(f0.z); v[3]=f2bs(f0.w);
        v[4]=f2bs(f1.x); v[5]=f2bs(f1.y); v[6]=f2bs(f1.z); v[7]=f2bs(f1.w);
        const int nt = n >> 7, rn = n & 127;
        const int kt = kc >> 3, c = kc & 7;
        *(u16x8*)(wbt + (((size_t)nt * 16 + kt) * 128 + rn) * 64 + ((c ^ (rn & 7)) * 8)) = v;
    }

    const int b = bh >> 4, h = bh & 15;
    const int r = t >> 2, cp = t & 3;

    __shared__ __align__(16) unsigned short Sm[64][72];

    const float* src = x + ((size_t)(b * LSEQ + lt * 64 + r)) * HDIM + h * DH + cp * 16;
    float4 f0 = *(const float4*)(src);
    float4 f1 = *(const float4*)(src + 4);
    float4 f2 = *(const float4*)(src + 8);
    float4 f3 = *(const float4*)(src + 12);
    u16x8 lo, hi;
    lo[0]=f2bs(f0.x); lo[1]=f2bs(f0.y); lo[2]=f2bs(f0.z); lo[3]=f2bs(f0.w);
    lo[4]=f2bs(f1.x); lo[5]=f2bs(f1.y); lo[6]=f2bs(f1.z); lo[7]=f2bs(f1.w);
    hi[0]=f2bs(f2.x); hi[1]=f2bs(f2.y); hi[2]=f2bs(f2.z); hi[3]=f2bs(f2.w);
    hi[4]=f2bs(f3.x); hi[5]=f2bs(f3.y); hi[6]=f2bs(f3.z); hi[7]=f2bs(f3.w);
    u16x8 slo, shi;
    slo[0]=f2bs(f0.x*QK_SCALE); slo[1]=f2bs(f0.y*QK_SCALE); slo[2]=f2bs(f0.z*QK_SCALE); slo[3]=f2bs(f0.w*QK_SCALE);
    slo[4]=f2bs(f1.x*QK_SCALE); slo[5]=f2bs(f1.y*QK_SCALE); slo[6]=f2bs(f1.z*QK_SCALE); slo[7]=f2bs(f1.w*QK_SCALE);
    shi[0]=f2bs(f2.x*QK_SCALE); shi[1]=f2bs(f2.y*QK_SCALE); shi[2]=f2bs(f2.z*QK_SCALE); shi[3]=f2bs(f2.w*QK_SCALE);
    shi[4]=f2bs(f3.x*QK_SCALE); shi[5]=f2bs(f3.y*QK_SCALE); shi[6]=f2bs(f3.z*QK_SCALE); shi[7]=f2bs(f3.w*QK_SCALE);

    {
        unsigned short* kt = xb + ((size_t)bid) * 4096;
        const int s  = r >> 4, rla = r & 15;
        const int ks = cp >> 1, q0 = (cp & 1) * 2;
        *(u16x8*)(kt + ((s * 2 + ks) * 64 + q0 * 16 + rla) * 8)       = slo;
        *(u16x8*)(kt + ((s * 2 + ks) * 64 + (q0 + 1) * 16 + rla) * 8) = shi;
    }
    *(u16x8*)&Sm[r][cp * 16]     = lo;
    *(u16x8*)&Sm[r][cp * 16 + 8] = hi;
    __syncthreads();

    {
        const int dt = t >> 6, lane = t & 63;
        const int la = lane & 15, quad = lane >> 4;
        u16x8 g0, g1;
        #pragma unroll
        for (int kvt = 0; kvt < 2; ++kvt)
            #pragma unroll
            for (int j = 0; j < 4; ++j)
                g0[kvt * 4 + j] = Sm[kvt * 16 + quad * 4 + j][dt * 16 + la];
        #pragma unroll
        for (int kvt = 0; kvt < 2; ++kvt)
            #pragma unroll
            for (int j = 0; j < 4; ++j)
                g1[kvt * 4 + j] = Sm[(kvt + 2) * 16 + quad * 4 + j][dt * 16 + la];
        unsigned short* vt = xt + ((size_t)bid) * 4096;
        *(u16x8*)(vt + (dt * 64 + lane) * 16)     = g0;
        *(u16x8*)(vt + (dt * 64 + lane) * 16 + 8) = g1;
    }
}

// ---------------------------------------------------------------------------
// Kernel 2: flash attention, transpose-free, 64-q blocks for occupancy.
// grid (32 bh, 32 qt) = 1024 blocks (4/CU), wave owns 16 q rows.
// Epilogue normalizes in-register, writes swizzled proj-A ctx tiles:
//   mt = b*16 + (qt>>1); rr = (qt&1)*64 + w*16 + la;
//   chunk c = dt*2 + (quad>>1) at (c ^ (rr&7)), in-chunk off (quad&1)*4.
// ---------------------------------------------------------------------------
__global__ __launch_bounds__(256) void attn_kernel(const unsigned short* __restrict__ xb,
                                                   const unsigned short* __restrict__ xt,
                                                   unsigned short* __restrict__ ctxt) {
    const int bh = blockIdx.x;
    const int qt = blockIdx.y;
    const int tid = threadIdx.x;
    const int w = tid >> 6, lane = tid & 63;
    const int la = lane & 15, quad = lane >> 4;

    __shared__ __align__(16) unsigned short KL[2][4096];
    __shared__ __align__(16) unsigned short VL[2][4096];

    const unsigned short* xbh = xb + (size_t)bh * 32 * 4096;
    const unsigned short* xth = xt + (size_t)bh * 32 * 4096;
    const int qbase = qt * 64 + w * 16;

    // Q B-frags (frag-major xb): q-tile s = (qbase>>4)&3 within tile qbase>>6
    bf16x8 qf[2];
    {
        const unsigned short* qs = xbh + (qbase >> 6) * 4096 + (((qbase >> 4) & 3) * 2) * 512;
        qf[0] = *(const bf16x8*)(qs + lane * 8);
        qf[1] = *(const bf16x8*)(qs + 512 + lane * 8);
    }

    const f32x4 fzero = {0.f, 0.f, 0.f, 0.f};
    f32x4 acc[4];
    #pragma unroll
    for (int j = 0; j < 4; ++j) acc[j] = fzero;
    float lp = 0.f;

    #pragma unroll
    for (int j = 0; j < 2; ++j) {
        const int off = (j * 256 + tid) * 16;
        GLOAD_LDS((const char*)xbh + off, (char*)KL[0] + off);
        GLOAD_LDS((const char*)xth + off, (char*)VL[0] + off);
    }
    __syncthreads();

    for (int tt = 0; tt < 32; ++tt) {
        if (tt < 31) {
            const char* ksrc = (const char*)(xbh + (tt + 1) * 4096);
            char* kdst = (char*)KL[(tt + 1) & 1];
            #pragma unroll
            for (int j = 0; j < 2; ++j) {
                const int off = (j * 256 + tid) * 16;
                GLOAD_LDS(ksrc + off, kdst + off);
            }
        }

        // --- S^T = K Q^T ---
        const unsigned short* kb = KL[tt & 1];
        f32x4 st[4];
        #pragma unroll
        for (int kvt = 0; kvt < 4; ++kvt) {
            bf16x8 kf0 = *(const bf16x8*)(kb + (kvt * 2 + 0) * 512 + lane * 8);
            bf16x8 kf1 = *(const bf16x8*)(kb + (kvt * 2 + 1) * 512 + lane * 8);
            f32x4 s = fzero;
            s = __builtin_amdgcn_mfma_f32_16x16x32_bf16(kf0, qf[0], s, 0, 0, 0);
            s = __builtin_amdgcn_mfma_f32_16x16x32_bf16(kf1, qf[1], s, 0, 0, 0);
            st[kvt] = s;
        }

        // --- exp2 + pack to register-resident B-frags ---
        bf16x4 pf[4];
        {
            float ls = 0.f;
            #pragma unroll
            for (int kvt = 0; kvt < 4; ++kvt) {
                float p0 = __builtin_amdgcn_exp2f(st[kvt][0]);
                float p1 = __builtin_amdgcn_exp2f(st[kvt][1]);
                float p2 = __builtin_amdgcn_exp2f(st[kvt][2]);
                float p3 = __builtin_amdgcn_exp2f(st[kvt][3]);
                ls += (p0 + p1) + (p2 + p3);
                uint32_t u0 = __float_as_uint(p0) + 0x8000u;
                uint32_t u1 = __float_as_uint(p1) + 0x8000u;
                uint32_t u2 = __float_as_uint(p2) + 0x8000u;
                uint32_t u3 = __float_as_uint(p3) + 0x8000u;
                union { uint2 u; bf16x4 v; } cv;
                cv.u = make_uint2(__builtin_amdgcn_perm(u1, u0, 0x07060302),
                                  __builtin_amdgcn_perm(u3, u2, 0x07060302));
                pf[kvt] = cv.v;
            }
            lp += ls;
        }

        __syncthreads();

        if (tt < 31) {
            const char* vsrc = (const char*)(xth + (tt + 1) * 4096);
            char* vdst = (char*)VL[(tt + 1) & 1];
            #pragma unroll
            for (int j = 0; j < 2; ++j) {
                const int off = (j * 256 + tid) * 16;
                GLOAD_LDS(vsrc + off, vdst + off);
            }
        }

        // --- O^T += V^T P^T (V frags read as b128 pairs, sliced) ---
        const unsigned short* vb = VL[tt & 1];
        #pragma unroll
        for (int dt = 0; dt < 4; ++dt) {
            const unsigned short* vrow = vb + (dt * 64 + lane) * 16;
            bf16x8 v01 = *(const bf16x8*)(vrow);       // kvt 0,1
            bf16x8 v23 = *(const bf16x8*)(vrow + 8);   // kvt 2,3
            bf16x4 vf0 = {v01[0], v01[1], v01[2], v01[3]};
            bf16x4 vf1 = {v01[4], v01[5], v01[6], v01[7]};
            bf16x4 vf2 = {v23[0], v23[1], v23[2], v23[3]};
            bf16x4 vf3 = {v23[4], v23[5], v23[6], v23[7]};
            f32x4 a = acc[dt];
            a = __builtin_amdgcn_mfma_f32_16x16x16bf16_1k(vf0, pf[0], a, 0, 0, 0);
            a = __builtin_amdgcn_mfma_f32_16x16x16bf16_1k(vf1, pf[1], a, 0, 0, 0);
            a = __builtin_amdgcn_mfma_f32_16x16x16bf16_1k(vf2, pf[2], a, 0, 0, 0);
            a = __builtin_amdgcn_mfma_f32_16x16x16bf16_1k(vf3, pf[3], a, 0, 0, 0);
            acc[dt] = a;
        }
    }

    // --- epilogue: normalize in-register, write swizzled proj-A ctx tiles ---
    const int b = bh >> 4, h = bh & 15;
    const int mt = b * 16 + (qt >> 1);
    unsigned short* tbase = ctxt + ((size_t)mt * 16 + h) * 128 * 64;
    {
        float l = lp;
        l += __shfl_xor(l, 16);
        l += __shfl_xor(l, 32);
        const float inv = 1.0f / l;          // l for q = qbase + la (uniform over quads)
        const int rr = (qt & 1) * 64 + w * 16 + la;
        unsigned short* rowp = tbase + rr * 64 + (quad & 1) * 4;
        #pragma unroll
        for (int dt = 0; dt < 4; ++dt) {
            f32x4 a = acc[dt];
            const int c = dt * 2 + (quad >> 1);
            *(ushort4*)(rowp + ((c ^ (rr & 7)) * 8)) =
                make_ushort4(f2bs(a[0] * inv), f2bs(a[1] * inv),
                             f2bs(a[2] * inv), f2bs(a[3] * inv));
        }
    }
}

// ---------------------------------------------------------------------------
// Kernel 3: out = ctx @ W^T + b. 128x128 tile, BK=64, double-buffered LDS,
// one barrier/iter, flat global_load_lds of pre-swizzled tiles.
// grid (8 n, 32 m), block 256 = 4 waves (2x2 64x64 quadrants).
// ---------------------------------------------------------------------------
__global__ __launch_bounds__(256) void proj_kernel(const unsigned short* __restrict__ ctxt,
                                                   const unsigned short* __restrict__ wbt,
                                                   const float* __restrict__ bias,
                                                   float* __restrict__ out) {
    const int ntb = blockIdx.x;
    const int mtb = blockIdx.y;
    const int tid = threadIdx.x;
    const int w = tid >> 6, lane = tid & 63;
    const int la = lane & 15, quad = lane >> 4;
    const int wm = (w >> 1) * 64, wn = (w & 1) * 64;

    __shared__ __align__(16) unsigned short As[2][8192];
    __shared__ __align__(16) unsigned short Bs[2][8192];

    const unsigned short* abase = ctxt + (size_t)mtb * 16 * 8192;
    const unsigned short* bbase = wbt  + (size_t)ntb * 16 * 8192;

    const int sw0 = ((quad)     ^ (la & 7)) * 8;
    const int sw1 = ((quad + 4) ^ (la & 7)) * 8;

    const f32x4 fzero = {0.f, 0.f, 0.f, 0.f};
    f32x4 acc[4][4];
    #pragma unroll
    for (int i = 0; i < 4; ++i)
        #pragma unroll
        for (int j = 0; j < 4; ++j) acc[i][j] = fzero;

    #pragma unroll
    for (int j = 0; j < 4; ++j) {
        const int fc = j * 256 + tid;
        GLOAD_LDS((const char*)abase + fc * 16, (char*)As[0] + fc * 16);
        GLOAD_LDS((const char*)bbase + fc * 16, (char*)Bs[0] + fc * 16);
    }
    __syncthreads();

    for (int kt = 0; kt < 16; ++kt) {
        if (kt < 15) {
            const char* asrc = (const char*)(abase + (kt + 1) * 8192);
            const char* bsrc = (const char*)(bbase + (kt + 1) * 8192);
            char* adst = (char*)As[(kt + 1) & 1];
            char* bdst = (char*)Bs[(kt + 1) & 1];
            #pragma unroll
            for (int j = 0; j < 4; ++j) {
                const int fc = j * 256 + tid;
                GLOAD_LDS(asrc + fc * 16, adst + fc * 16);
                GLOAD_LDS(bsrc + fc * 16, bdst + fc * 16);
            }
        }

        const unsigned short* Ab = As[kt & 1];
        const unsigned short* Bb = Bs[kt & 1];
        #pragma unroll
        for (int ks2 = 0; ks2 < 2; ++ks2) {
            const int sw = ks2 ? sw1 : sw0;
            bf16x8 af[4], bfr[4];
            #pragma unroll
            for (int mt = 0; mt < 4; ++mt) af[mt]  = *(const bf16x8*)&Ab[(wm + mt * 16 + la) * 64 + sw];
            #pragma unroll
            for (int nt = 0; nt < 4; ++nt) bfr[nt] = *(const bf16x8*)&Bb[(wn + nt * 16 + la) * 64 + sw];
            #pragma unroll
            for (int mt = 0; mt < 4; ++mt)
                #pragma unroll
                for (int nt = 0; nt < 4; ++nt)
                    acc[mt][nt] = __builtin_amdgcn_mfma_f32_16x16x32_bf16(af[mt], bfr[nt], acc[mt][nt], 0, 0, 0);
        }
        __syncthreads();
    }

    const int m0 = mtb * 128, n0 = ntb * 128;
    #pragma unroll
    for (int nt = 0; nt < 4; ++nt) {
        const int n = n0 + wn + nt * 16 + la;
        const float bv = bias[n];
        #pragma unroll
        for (int mt = 0; mt < 4; ++mt)
            #pragma unroll
            for (int r = 0; r < 4; ++r) {
                const int m = m0 + wm + mt * 16 + quad * 4 + r;
                out[(size_t)m * HDIM + n] = acc[mt][nt][r] + bv;
            }
    }
}

// ---------------------------------------------------------------------------
extern "C" void kernel_launch(void* const* d_in, const int* in_sizes, int n_in,
                              void* d_out, int out_size, void* d_ws, size_t ws_size,
                              hipStream_t stream) {
    const float* x    = (const float*)d_in[0];
    const float* W    = (const float*)d_in[1];
    const float* bias = (const float*)d_in[2];
    float* out = (float*)d_out;

    // ws layout (bytes): ctxt 8M | xb 8M | xt 8M | wbt 2M
    unsigned short* ctxt = (unsigned short*)d_ws;
    unsigned short* xbp  = (unsigned short*)((char*)d_ws + ( 8u << 20));
    unsigned short* xtp  = (unsigned short*)((char*)d_ws + (16u << 20));
    unsigned short* wbt  = (unsigned short*)((char*)d_ws + (24u << 20));

    prep_kernel<<<dim3(32, 32), 256, 0, stream>>>(x, W, xbp, xtp, wbt);
    attn_kernel<<<dim3(32, 32), 256, 0, stream>>>(xbp, xtp, ctxt);
    proj_kernel<<<dim3(8, 32), 256, 0, stream>>>(ctxt, wbt, bias, out);
}

// Round 12
// 146.433 us; speedup vs baseline: 1.0888x; 1.0182x over previous
//
#include <hip/hip_runtime.h>
#include <stdint.h>

#define NH     16
#define LSEQ   2048
#define DH     64
#define HDIM   1024
#define BATCH  2

typedef __attribute__((ext_vector_type(8))) short bf16x8;
typedef __attribute__((ext_vector_type(4))) short bf16x4;
typedef __attribute__((ext_vector_type(8))) unsigned short u16x8;
typedef __attribute__((ext_vector_type(4))) float f32x4;

// fp32 -> bf16 (RNE)
static __device__ inline unsigned short f2bs(float f) {
    union { float f; uint32_t u; } v; v.f = f;
    uint32_t u = v.u;
    return (unsigned short)((u + 0x7FFFu + ((u >> 16) & 1u)) >> 16);
}

#define GLOAD_LDS(gp, lp) \
    __builtin_amdgcn_global_load_lds((const __attribute__((address_space(1))) void*)(gp), \
                                     (__attribute__((address_space(3))) void*)(lp), 16, 0, 0)

// sqrt(0.125 * log2(e)) — folded into xb so (sQ)·(sK) carries the softmax scale
#define QK_SCALE 0.42466083f

// ---------------------------------------------------------------------------
// Kernel 1: prep. grid (32 lt, 32 bh) = 1024 blocks, 256 thr.
//  a) threads 0..127: W fp32 -> bf16 swizzled 128x64 tiles (128 chunks/block)
//  b) all threads: x -> xb (frag-major Q/K, scaled) and xt (frag-major V^T)
// ---------------------------------------------------------------------------
__global__ __launch_bounds__(256) void prep_kernel(const float* __restrict__ x,
                                                   const float* __restrict__ W,
                                                   unsigned short* __restrict__ xb,
                                                   unsigned short* __restrict__ xt,
                                                   unsigned short* __restrict__ wbt) {
    const int lt = blockIdx.x, bh = blockIdx.y;
    const int bid = bh * 32 + lt;
    const int t = threadIdx.x;

    if (t < 128) {
        const int gid = bid * 128 + t;
        const int n  = gid >> 7;
        const int kc = gid & 127;
        const float* src = W + (size_t)n * 1024 + kc * 8;
        float4 f0 = *(const float4*)(src);
        float4 f1 = *(const float4*)(src + 4);
        u16x8 v;
        v[0]=f2bs(f0.x); v[1]=f2bs(f0.y); v[2]=f2bs(f0.z); v[3]=f2bs(f0.w);
        v[4]=f2bs(f1.x); v[5]=f2bs(f1.y); v[6]=f2bs(f1.z); v[7]=f2bs(f1.w);
        const int nt = n >> 7, rn = n & 127;
        const int kt = kc >> 3, c = kc & 7;
        *(u16x8*)(wbt + (((size_t)nt * 16 + kt) * 128 + rn) * 64 + ((c ^ (rn & 7)) * 8)) = v;
    }

    const int b = bh >> 4, h = bh & 15;
    const int r = t >> 2, cp = t & 3;

    __shared__ __align__(16) unsigned short Sm[64][72];

    const float* src = x + ((size_t)(b * LSEQ + lt * 64 + r)) * HDIM + h * DH + cp * 16;
    float4 f0 = *(const float4*)(src);
    float4 f1 = *(const float4*)(src + 4);
    float4 f2 = *(const float4*)(src + 8);
    float4 f3 = *(const float4*)(src + 12);
    u16x8 lo, hi;
    lo[0]=f2bs(f0.x); lo[1]=f2bs(f0.y); lo[2]=f2bs(f0.z); lo[3]=f2bs(f0.w);
    lo[4]=f2bs(f1.x); lo[5]=f2bs(f1.y); lo[6]=f2bs(f1.z); lo[7]=f2bs(f1.w);
    hi[0]=f2bs(f2.x); hi[1]=f2bs(f2.y); hi[2]=f2bs(f2.z); hi[3]=f2bs(f2.w);
    hi[4]=f2bs(f3.x); hi[5]=f2bs(f3.y); hi[6]=f2bs(f3.z); hi[7]=f2bs(f3.w);
    u16x8 slo, shi;
    slo[0]=f2bs(f0.x*QK_SCALE); slo[1]=f2bs(f0.y*QK_SCALE); slo[2]=f2bs(f0.z*QK_SCALE); slo[3]=f2bs(f0.w*QK_SCALE);
    slo[4]=f2bs(f1.x*QK_SCALE); slo[5]=f2bs(f1.y*QK_SCALE); slo[6]=f2bs(f1.z*QK_SCALE); slo[7]=f2bs(f1.w*QK_SCALE);
    shi[0]=f2bs(f2.x*QK_SCALE); shi[1]=f2bs(f2.y*QK_SCALE); shi[2]=f2bs(f2.z*QK_SCALE); shi[3]=f2bs(f2.w*QK_SCALE);
    shi[4]=f2bs(f3.x*QK_SCALE); shi[5]=f2bs(f3.y*QK_SCALE); shi[6]=f2bs(f3.z*QK_SCALE); shi[7]=f2bs(f3.w*QK_SCALE);

    {
        unsigned short* kt = xb + ((size_t)bid) * 4096;
        const int s  = r >> 4, rla = r & 15;
        const int ks = cp >> 1, q0 = (cp & 1) * 2;
        *(u16x8*)(kt + ((s * 2 + ks) * 64 + q0 * 16 + rla) * 8)       = slo;
        *(u16x8*)(kt + ((s * 2 + ks) * 64 + (q0 + 1) * 16 + rla) * 8) = shi;
    }
    *(u16x8*)&Sm[r][cp * 16]     = lo;
    *(u16x8*)&Sm[r][cp * 16 + 8] = hi;
    __syncthreads();

    {
        const int dt = t >> 6, lane = t & 63;
        const int la = lane & 15, quad = lane >> 4;
        u16x8 g0, g1;
        #pragma unroll
        for (int kvt = 0; kvt < 2; ++kvt)
            #pragma unroll
            for (int j = 0; j < 4; ++j)
                g0[kvt * 4 + j] = Sm[kvt * 16 + quad * 4 + j][dt * 16 + la];
        #pragma unroll
        for (int kvt = 0; kvt < 2; ++kvt)
            #pragma unroll
            for (int j = 0; j < 4; ++j)
                g1[kvt * 4 + j] = Sm[(kvt + 2) * 16 + quad * 4 + j][dt * 16 + la];
        unsigned short* vt = xt + ((size_t)bid) * 4096;
        *(u16x8*)(vt + (dt * 64 + lane) * 16)     = g0;
        *(u16x8*)(vt + (dt * 64 + lane) * 16 + 8) = g1;
    }
}

// ---------------------------------------------------------------------------
// Kernel 2: flash attention, transpose-free, 64-q blocks (4 blocks/CU).
// grid (32 bh, 32 qt) = 1024 blocks, wave owns 16 q rows.
// r12: direct bf16x4 V-frag LDS loads (no slicing), truncation pack (no
// +0x8000), pointer-incremented staging addresses.
// ---------------------------------------------------------------------------
__global__ __launch_bounds__(256) void attn_kernel(const unsigned short* __restrict__ xb,
                                                   const unsigned short* __restrict__ xt,
                                                   unsigned short* __restrict__ ctxt) {
    const int bh = blockIdx.x;
    const int qt = blockIdx.y;
    const int tid = threadIdx.x;
    const int w = tid >> 6, lane = tid & 63;
    const int la = lane & 15, quad = lane >> 4;

    __shared__ __align__(16) unsigned short KL[2][4096];
    __shared__ __align__(16) unsigned short VL[2][4096];

    const unsigned short* xbh = xb + (size_t)bh * 32 * 4096;
    const unsigned short* xth = xt + (size_t)bh * 32 * 4096;
    const int qbase = qt * 64 + w * 16;

    bf16x8 qf[2];
    {
        const unsigned short* qs = xbh + (qbase >> 6) * 4096 + (((qbase >> 4) & 3) * 2) * 512;
        qf[0] = *(const bf16x8*)(qs + lane * 8);
        qf[1] = *(const bf16x8*)(qs + 512 + lane * 8);
    }

    const f32x4 fzero = {0.f, 0.f, 0.f, 0.f};
    f32x4 acc[4];
    #pragma unroll
    for (int j = 0; j < 4; ++j) acc[j] = fzero;
    float lp = 0.f;

    const int soff = tid * 16;                 // this thread's 16B staging slot
    #pragma unroll
    for (int j = 0; j < 2; ++j) {
        const int off = j * 4096 + soff;
        GLOAD_LDS((const char*)xbh + off, (char*)KL[0] + off);
        GLOAD_LDS((const char*)xth + off, (char*)VL[0] + off);
    }
    __syncthreads();

    // incremented staging source pointers (tile t+1)
    const char* kp = (const char*)xbh + 8192;
    const char* vp = (const char*)xth + 8192;

    for (int tt = 0; tt < 32; ++tt) {
        if (tt < 31) {
            char* kdst = (char*)KL[(tt + 1) & 1];
            GLOAD_LDS(kp + soff,        kdst + soff);
            GLOAD_LDS(kp + 4096 + soff, kdst + 4096 + soff);
        }

        // --- S^T = K Q^T ---
        const unsigned short* kb = KL[tt & 1];
        f32x4 st[4];
        #pragma unroll
        for (int kvt = 0; kvt < 4; ++kvt) {
            bf16x8 kf0 = *(const bf16x8*)(kb + (kvt * 2 + 0) * 512 + lane * 8);
            bf16x8 kf1 = *(const bf16x8*)(kb + (kvt * 2 + 1) * 512 + lane * 8);
            f32x4 s = fzero;
            s = __builtin_amdgcn_mfma_f32_16x16x32_bf16(kf0, qf[0], s, 0, 0, 0);
            s = __builtin_amdgcn_mfma_f32_16x16x32_bf16(kf1, qf[1], s, 0, 0, 0);
            st[kvt] = s;
        }

        // --- exp2 + truncation pack to register-resident B-frags ---
        bf16x4 pf[4];
        {
            float ls = 0.f;
            #pragma unroll
            for (int kvt = 0; kvt < 4; ++kvt) {
                float p0 = __builtin_amdgcn_exp2f(st[kvt][0]);
                float p1 = __builtin_amdgcn_exp2f(st[kvt][1]);
                float p2 = __builtin_amdgcn_exp2f(st[kvt][2]);
                float p3 = __builtin_amdgcn_exp2f(st[kvt][3]);
                ls += (p0 + p1) + (p2 + p3);
                union { uint2 u; bf16x4 v; } cv;
                cv.u = make_uint2(
                    __builtin_amdgcn_perm(__float_as_uint(p1), __float_as_uint(p0), 0x07060302),
                    __builtin_amdgcn_perm(__float_as_uint(p3), __float_as_uint(p2), 0x07060302));
                pf[kvt] = cv.v;
            }
            lp += ls;
        }

        __syncthreads();

        if (tt < 31) {
            char* vdst = (char*)VL[(tt + 1) & 1];
            GLOAD_LDS(vp + soff,        vdst + soff);
            GLOAD_LDS(vp + 4096 + soff, vdst + 4096 + soff);
            kp += 8192;
            vp += 8192;
        }

        // --- O^T += V^T P^T (direct bf16x4 LDS loads, no slicing) ---
        const unsigned short* vb = VL[tt & 1];
        #pragma unroll
        for (int dt = 0; dt < 4; ++dt) {
            const unsigned short* vrow = vb + (dt * 64 + lane) * 16;
            bf16x4 vf0 = *(const bf16x4*)(vrow);
            bf16x4 vf1 = *(const bf16x4*)(vrow + 4);
            bf16x4 vf2 = *(const bf16x4*)(vrow + 8);
            bf16x4 vf3 = *(const bf16x4*)(vrow + 12);
            f32x4 a = acc[dt];
            a = __builtin_amdgcn_mfma_f32_16x16x16bf16_1k(vf0, pf[0], a, 0, 0, 0);
            a = __builtin_amdgcn_mfma_f32_16x16x16bf16_1k(vf1, pf[1], a, 0, 0, 0);
            a = __builtin_amdgcn_mfma_f32_16x16x16bf16_1k(vf2, pf[2], a, 0, 0, 0);
            a = __builtin_amdgcn_mfma_f32_16x16x16bf16_1k(vf3, pf[3], a, 0, 0, 0);
            acc[dt] = a;
        }
    }

    // --- epilogue: normalize in-register, write swizzled proj-A ctx tiles ---
    const int b = bh >> 4, h = bh & 15;
    const int mt = b * 16 + (qt >> 1);
    unsigned short* tbase = ctxt + ((size_t)mt * 16 + h) * 128 * 64;
    {
        float l = lp;
        l += __shfl_xor(l, 16);
        l += __shfl_xor(l, 32);
        const float inv = 1.0f / l;
        const int rr = (qt & 1) * 64 + w * 16 + la;
        unsigned short* rowp = tbase + rr * 64 + (quad & 1) * 4;
        #pragma unroll
        for (int dt = 0; dt < 4; ++dt) {
            f32x4 a = acc[dt];
            const int c = dt * 2 + (quad >> 1);
            *(ushort4*)(rowp + ((c ^ (rr & 7)) * 8)) =
                make_ushort4(f2bs(a[0] * inv), f2bs(a[1] * inv),
                             f2bs(a[2] * inv), f2bs(a[3] * inv));
        }
    }
}

// ---------------------------------------------------------------------------
// Kernel 3: out = ctx @ W^T + b. 128x128 tile, BK=64, double-buffered LDS,
// one barrier/iter, flat global_load_lds of pre-swizzled tiles.
// grid (8 n, 32 m), block 256 = 4 waves (2x2 64x64 quadrants).
// ---------------------------------------------------------------------------
__global__ __launch_bounds__(256) void proj_kernel(const unsigned short* __restrict__ ctxt,
                                                   const unsigned short* __restrict__ wbt,
                                                   const float* __restrict__ bias,
                                                   float* __restrict__ out) {
    const int ntb = blockIdx.x;
    const int mtb = blockIdx.y;
    const int tid = threadIdx.x;
    const int w = tid >> 6, lane = tid & 63;
    const int la = lane & 15, quad = lane >> 4;
    const int wm = (w >> 1) * 64, wn = (w & 1) * 64;

    __shared__ __align__(16) unsigned short As[2][8192];
    __shared__ __align__(16) unsigned short Bs[2][8192];

    const unsigned short* abase = ctxt + (size_t)mtb * 16 * 8192;
    const unsigned short* bbase = wbt  + (size_t)ntb * 16 * 8192;

    const int sw0 = ((quad)     ^ (la & 7)) * 8;
    const int sw1 = ((quad + 4) ^ (la & 7)) * 8;

    const f32x4 fzero = {0.f, 0.f, 0.f, 0.f};
    f32x4 acc[4][4];
    #pragma unroll
    for (int i = 0; i < 4; ++i)
        #pragma unroll
        for (int j = 0; j < 4; ++j) acc[i][j] = fzero;

    #pragma unroll
    for (int j = 0; j < 4; ++j) {
        const int fc = j * 256 + tid;
        GLOAD_LDS((const char*)abase + fc * 16, (char*)As[0] + fc * 16);
        GLOAD_LDS((const char*)bbase + fc * 16, (char*)Bs[0] + fc * 16);
    }
    __syncthreads();

    for (int kt = 0; kt < 16; ++kt) {
        if (kt < 15) {
            const char* asrc = (const char*)(abase + (kt + 1) * 8192);
            const char* bsrc = (const char*)(bbase + (kt + 1) * 8192);
            char* adst = (char*)As[(kt + 1) & 1];
            char* bdst = (char*)Bs[(kt + 1) & 1];
            #pragma unroll
            for (int j = 0; j < 4; ++j) {
                const int fc = j * 256 + tid;
                GLOAD_LDS(asrc + fc * 16, adst + fc * 16);
                GLOAD_LDS(bsrc + fc * 16, bdst + fc * 16);
            }
        }

        const unsigned short* Ab = As[kt & 1];
        const unsigned short* Bb = Bs[kt & 1];
        #pragma unroll
        for (int ks2 = 0; ks2 < 2; ++ks2) {
            const int sw = ks2 ? sw1 : sw0;
            bf16x8 af[4], bfr[4];
            #pragma unroll
            for (int mt = 0; mt < 4; ++mt) af[mt]  = *(const bf16x8*)&Ab[(wm + mt * 16 + la) * 64 + sw];
            #pragma unroll
            for (int nt = 0; nt < 4; ++nt) bfr[nt] = *(const bf16x8*)&Bb[(wn + nt * 16 + la) * 64 + sw];
            #pragma unroll
            for (int mt = 0; mt < 4; ++mt)
                #pragma unroll
                for (int nt = 0; nt < 4; ++nt)
                    acc[mt][nt] = __builtin_amdgcn_mfma_f32_16x16x32_bf16(af[mt], bfr[nt], acc[mt][nt], 0, 0, 0);
        }
        __syncthreads();
    }

    const int m0 = mtb * 128, n0 = ntb * 128;
    #pragma unroll
    for (int nt = 0; nt < 4; ++nt) {
        const int n = n0 + wn + nt * 16 + la;
        const float bv = bias[n];
        #pragma unroll
        for (int mt = 0; mt < 4; ++mt)
            #pragma unroll
            for (int r = 0; r < 4; ++r) {
                const int m = m0 + wm + mt * 16 + quad * 4 + r;
                out[(size_t)m * HDIM + n] = acc[mt][nt][r] + bv;
            }
    }
}

// ---------------------------------------------------------------------------
extern "C" void kernel_launch(void* const* d_in, const int* in_sizes, int n_in,
                              void* d_out, int out_size, void* d_ws, size_t ws_size,
                              hipStream_t stream) {
    const float* x    = (const float*)d_in[0];
    const float* W    = (const float*)d_in[1];
    const float* bias = (const float*)d_in[2];
    float* out = (float*)d_out;

    // ws layout (bytes): ctxt 8M | xb 8M | xt 8M | wbt 2M
    unsigned short* ctxt = (unsigned short*)d_ws;
    unsigned short* xbp  = (unsigned short*)((char*)d_ws + ( 8u << 20));
    unsigned short* xtp  = (unsigned short*)((char*)d_ws + (16u << 20));
    unsigned short* wbt  = (unsigned short*)((char*)d_ws + (24u << 20));

    prep_kernel<<<dim3(32, 32), 256, 0, stream>>>(x, W, xbp, xtp, wbt);
    attn_kernel<<<dim3(32, 32), 256, 0, stream>>>(xbp, xtp, ctxt);
    proj_kernel<<<dim3(8, 32), 256, 0, stream>>>(ctxt, wbt, bias, out);
}